// Round 11
// baseline (376.262 us; speedup 1.0000x reference)
//
#include <hip/hip_runtime.h>
#include <hip/hip_bf16.h>

typedef unsigned short u16;
typedef unsigned int u32;
typedef unsigned long long u64;
typedef __attribute__((ext_vector_type(8))) short short8;
typedef __attribute__((ext_vector_type(4))) short s16x4;
typedef __attribute__((ext_vector_type(4))) float f32x4;

// ---------- helpers ----------
__device__ __forceinline__ float bf2f(u16 u){
  union { unsigned int i; float f; } v; v.i = ((unsigned int)u) << 16; return v.f;
}
__device__ __forceinline__ u16 f2bf(float f){
  union { float f; unsigned int i; } v; v.f = f;
  unsigned int x = v.i;
  return (u16)((x + 0x7fffu + ((x >> 16) & 1u)) >> 16);
}
__device__ __forceinline__ float gelu_exact(float x){
  return 0.5f * x * (1.0f + erff(x * 0.70710678118654752440f));
}
__device__ __forceinline__ void gld16(const void* g, void* l){
  __builtin_amdgcn_global_load_lds((const __attribute__((address_space(1))) void*)g,
                                   (__attribute__((address_space(3))) void*)l, 16, 0, 0);
}

// 16x16x16 bf16 MFMA (K=16): A-frag lane(lq,lm) holds A[lm][4*lq+e], e=0..3.
__device__ __forceinline__ f32x4 mfma16x16x16bf16(s16x4 a, s16x4 b, f32x4 c){
#if __has_builtin(__builtin_amdgcn_mfma_f32_16x16x16_bf16)
  return __builtin_amdgcn_mfma_f32_16x16x16_bf16(a, b, c, 0, 0, 0);
#elif __has_builtin(__builtin_amdgcn_mfma_f32_16x16x16bf16_1k)
  return __builtin_amdgcn_mfma_f32_16x16x16bf16_1k(a, b, c, 0, 0, 0);
#else
  asm volatile("v_mfma_f32_16x16x16_bf16 %0, %1, %2, %3\n\ts_nop 7\n\ts_nop 3"
               : "=v"(c) : "v"(a), "v"(b), "v"(c));
  return c;
#endif
}

// B=32 N=320 C=768 H=12 S=256 T=64 hd=64; ALL I/O fp32.

// ---------- merged fp32->bf16 converts (x | qkv_w | proj_w) ----------
__global__ void k_cvt3(const float* __restrict__ s0, u16* __restrict__ d0,
                       const float* __restrict__ s1, u16* __restrict__ d1,
                       const float* __restrict__ s2, u16* __restrict__ d2){
  int bx = blockIdx.x;
  const float* src; u16* dst; int i;
  if (bx < 7680){ src = s0; dst = d0; i = bx*256 + threadIdx.x; }
  else if (bx < 9408){ src = s1; dst = d1; i = (bx - 7680)*256 + threadIdx.x; }
  else { src = s2; dst = d2; i = (bx - 9408)*256 + threadIdx.x; }
  float4 v = ((const float4*)src)[i];
  ushort4 p; p.x = f2bf(v.x); p.y = f2bf(v.y); p.z = f2bf(v.z); p.w = f2bf(v.w);
  ((ushort4*)dst)[i] = p;
}

// ---------- tgt_rep[b][c] = mean_t(x[b,t,c]*mask[b,t]) ----------
__global__ void k_tgt(const float* __restrict__ x, const float* __restrict__ tmask,
                      float* __restrict__ tgt){
  int b = blockIdx.x;
  int c = blockIdx.y*64 + threadIdx.x;
  float s = 0.f;
  for (int t = 0; t < 64; ++t)
    s += x[(size_t)(b*320 + t)*768 + c] * tmask[b*64 + t];
  tgt[b*768 + c] = s * (1.0f/64.0f);
}

// ---------- tgtdp[b][o] = dp1_b[o] + sum_c tgt[b][c]*dp1_w[o][768+c] ----------
__global__ void k_tgtdp(const float* __restrict__ tgt, const float* __restrict__ w1,
                        const float* __restrict__ b1, float* __restrict__ tgtdp){
  int b = blockIdx.x; int o = threadIdx.x;   // blockDim = 384
  float s = b1[o];
  const float* wr = w1 + (size_t)o*1536 + 768;
  const float* tr = tgt + b*768;
  for (int c = 0; c < 768; ++c) s += tr[c] * wr[c];
  tgtdp[b*384 + o] = s;
}

// ---------- FUSED: dp1 fp32 SGEMM (v0) + qkv bf16 MFMA GEMM (r6) ----------
// INTERLEAVED block mapping: 2208 = 96 groups x 23; per group the first 8
// blocks are dp1 (768 total), the last 15 are qkv (1440 total). Every CU
// holds a VALU-pipe + MFMA-pipe mix for the whole kernel (m114 co-schedule).
// Both paths byte-identical to their verified forms -> outputs bit-identical.
__global__ __launch_bounds__(256, 2)
void k_fused1(const float* __restrict__ A, const float* __restrict__ BT,
              const float* __restrict__ tgtdp, float* __restrict__ h1,
              const u16* __restrict__ GA, const u16* __restrict__ GB,
              const float* __restrict__ bias,
              u16* __restrict__ Qg, u16* __restrict__ Kg, u16* __restrict__ Vg)
{
  __shared__ char smem[32768];
  int bx = blockIdx.x;
  int t = threadIdx.x;
  int grp = bx / 23, lane23 = bx % 23;
  if (lane23 < 8){
    // ================= dp1 sgemm path (v0); idx 0..767 =================
    int idx = grp*8 + lane23;
    float (*As)[68] = (float(*)[68])smem;
    float (*Bs)[68] = (float(*)[68])(smem + 4352);
    int mB = (idx & 127)*64, nB = (idx >> 7)*64;
    int tx = t & 15, ty = t >> 4;
    float acc[4][4] = {};
    for (int k0 = 0; k0 < 768; k0 += 16){
      __syncthreads();
      {
        int m = t >> 2, kc = (t & 3) * 4;
        int ga = mB + m;
        ga = ((ga >> 8) * 320) + 64 + (ga & 255);       // REMAP
        float4 av = *(const float4*)&A[(size_t)ga*768 + k0 + kc];
        As[kc+0][m] = av.x; As[kc+1][m] = av.y; As[kc+2][m] = av.z; As[kc+3][m] = av.w;
        float4 bv = *(const float4*)&BT[(size_t)(nB+m)*1536 + k0 + kc];
        Bs[kc+0][m] = bv.x; Bs[kc+1][m] = bv.y; Bs[kc+2][m] = bv.z; Bs[kc+3][m] = bv.w;
      }
      __syncthreads();
      #pragma unroll
      for (int k = 0; k < 16; ++k){
        float4 av = *(const float4*)&As[k][ty*4];
        float4 bv = *(const float4*)&Bs[k][tx*4];
        float a4[4] = {av.x, av.y, av.z, av.w};
        float b4[4] = {bv.x, bv.y, bv.z, bv.w};
        #pragma unroll
        for (int i = 0; i < 4; ++i)
          #pragma unroll
          for (int j = 0; j < 4; ++j)
            acc[i][j] += a4[i] * b4[j];
      }
    }
    #pragma unroll
    for (int i = 0; i < 4; ++i){
      int row = mB + ty*4 + i;
      #pragma unroll
      for (int j = 0; j < 4; ++j){
        int n = nB + tx*4 + j;
        float base = tgtdp[(row >> 8)*384 + n];
        h1[(size_t)row*384 + n] = gelu_exact(acc[i][j] + base);
      }
    }
  } else {
    // ================= qkv bf16 MFMA path (r6); idx 0..1439 =================
    int i2 = grp*15 + (lane23 - 8);
    u16* As = (u16*)smem;            // [128][64] swizzled
    u16* Bs = (u16*)(smem + 16384);
    int mB = (i2 % 80)*128, nB = (i2 / 80)*128;
    int w = t >> 6, l = t & 63;
    int wr = w >> 1, wc = w & 1;
    int lm = l & 15, lq = l >> 4;

    f32x4 zero4 = {0.f,0.f,0.f,0.f};
    f32x4 acc[4][4];
    #pragma unroll
    for (int i = 0; i < 4; ++i)
      #pragma unroll
      for (int j = 0; j < 4; ++j) acc[i][j] = zero4;

    int srow = t >> 3;            // 0..31 within shot
    int su0  = t & 7;             // phys unit this lane fills
    for (int k0 = 0; k0 < 768; k0 += 64){
      __syncthreads();
      #pragma unroll
      for (int s = 0; s < 4; ++s){
        int row = s*32 + srow;
        int su  = su0 ^ (row & 7);
        gld16(&GA[(size_t)(mB+row)*768 + k0 + su*8], (char*)As + s*4096 + w*1024);
        gld16(&GB[(size_t)(nB+row)*768 + k0 + su*8], (char*)Bs + s*4096 + w*1024);
      }
      __syncthreads();
      short8 af[4][2], bfv[4][2];
      #pragma unroll
      for (int mt = 0; mt < 4; ++mt){
        int r = wr*64 + mt*16 + lm;
        #pragma unroll
        for (int hh = 0; hh < 2; ++hh)
          af[mt][hh] = *(const short8*)&As[r*64 + (((hh*4 + lq) ^ (r & 7)) << 3)];
      }
      #pragma unroll
      for (int nt = 0; nt < 4; ++nt){
        int r = wc*64 + nt*16 + lm;
        #pragma unroll
        for (int hh = 0; hh < 2; ++hh)
          bfv[nt][hh] = *(const short8*)&Bs[r*64 + (((hh*4 + lq) ^ (r & 7)) << 3)];
      }
      #pragma unroll
      for (int mt = 0; mt < 4; ++mt)
        #pragma unroll
        for (int nt = 0; nt < 4; ++nt){
          acc[mt][nt] = __builtin_amdgcn_mfma_f32_16x16x32_bf16(af[mt][0], bfv[nt][0], acc[mt][nt], 0, 0, 0);
          acc[mt][nt] = __builtin_amdgcn_mfma_f32_16x16x32_bf16(af[mt][1], bfv[nt][1], acc[mt][nt], 0, 0, 0);
        }
    }
    // epilogue: C layout col=lane&15, row=(lane>>4)*4+reg
    #pragma unroll
    for (int mt = 0; mt < 4; ++mt){
      #pragma unroll
      for (int nt = 0; nt < 4; ++nt){
        int coln  = nB + wc*64 + nt*16 + lm;
        int rbase = mB + wr*64 + mt*16 + lq*4;
        float bv = bias[coln];
        int bidx = rbase / 320;
        int j = rbase - bidx*320;
        if (coln >= 1536){
          int h = (coln - 1536) >> 6, d = coln & 63;
          ushort4 pk;
          pk.x = f2bf(acc[mt][nt][0] + bv);
          pk.y = f2bf(acc[mt][nt][1] + bv);
          pk.z = f2bf(acc[mt][nt][2] + bv);
          pk.w = f2bf(acc[mt][nt][3] + bv);
          *(ushort4*)&Vg[((size_t)(bidx*12 + h)*64 + d)*320 + j] = pk;
        } else {
          bool isq = coln < 768;
          int ch = isq ? coln : (coln - 768);
          int h = ch >> 6, d = ch & 63;
          u16* dst = isq ? Qg : Kg;
          #pragma unroll
          for (int r = 0; r < 4; ++r)
            dst[((size_t)(bidx*12 + h)*320 + (j + r))*64 + d] = f2bf(acc[mt][nt][r] + bv);
        }
      }
    }
  }
}

// ---------- FUSED: dp2 fp32 SGEMM (v0) + vsum ----------
// Blocks 0..383: dp2 (M=8192 N=192 K=384, HASB). Blocks 384..767: vsum.
// vsumg now lives in the DEAD xb region (ws+19032064) — NO overlap with h2
// (12730368..19021824), unlike the r10 bug where vsumg clobbered h2's last
// 128 rows before k_decide read them.
__global__ __launch_bounds__(256)
void k_fused2(const float* __restrict__ A, const float* __restrict__ BT,
              const float* __restrict__ bias, float* __restrict__ out,
              const u16* __restrict__ Vg, float* __restrict__ vsumg)
{
  __shared__ char smem[8704];
  int bx = blockIdx.x;
  int t = threadIdx.x;
  if (bx < 384){
    // ---- dp2 sgemm v0: mB=(bx&127)*64, nB=(bx>>7)*64 ----
    float (*As)[68] = (float(*)[68])smem;
    float (*Bs)[68] = (float(*)[68])(smem + 4352);
    int mB = (bx & 127)*64, nB = (bx >> 7)*64;
    int tx = t & 15, ty = t >> 4;
    float acc[4][4] = {};
    for (int k0 = 0; k0 < 384; k0 += 16){
      __syncthreads();
      {
        int m = t >> 2, kc = (t & 3) * 4;
        float4 av = *(const float4*)&A[(size_t)(mB+m)*384 + k0 + kc];
        As[kc+0][m] = av.x; As[kc+1][m] = av.y; As[kc+2][m] = av.z; As[kc+3][m] = av.w;
        float4 bv = *(const float4*)&BT[(size_t)(nB+m)*384 + k0 + kc];
        Bs[kc+0][m] = bv.x; Bs[kc+1][m] = bv.y; Bs[kc+2][m] = bv.z; Bs[kc+3][m] = bv.w;
      }
      __syncthreads();
      #pragma unroll
      for (int k = 0; k < 16; ++k){
        float4 av = *(const float4*)&As[k][ty*4];
        float4 bv = *(const float4*)&Bs[k][tx*4];
        float a4[4] = {av.x, av.y, av.z, av.w};
        float b4[4] = {bv.x, bv.y, bv.z, bv.w};
        #pragma unroll
        for (int i = 0; i < 4; ++i)
          #pragma unroll
          for (int j = 0; j < 4; ++j)
            acc[i][j] += a4[i] * b4[j];
      }
    }
    #pragma unroll
    for (int i = 0; i < 4; ++i){
      int row = mB + ty*4 + i;
      #pragma unroll
      for (int j = 0; j < 4; ++j){
        int n = nB + tx*4 + j;
        out[(size_t)row*192 + n] = gelu_exact(acc[i][j] + bias[n]);
      }
    }
  } else {
    // ---- vsum: bh = bx - 384 ----
    float (*vsp)[64] = (float(*)[64])smem;
    int bh = bx - 384;
    int w = t >> 6, l = t & 63;
    const u16* vr = Vg + (size_t)bh*64*320 + (size_t)l*320 + w*80;
    float s = 0.f;
    for (int j8 = 0; j8 < 10; ++j8){
      short8 v = *(const short8*)&vr[j8*8];
      #pragma unroll
      for (int e = 0; e < 8; ++e) s += bf2f((u16)v[e]);
    }
    vsp[w][l] = s;
    __syncthreads();
    if (t < 64) vsumg[bh*64 + t] = (vsp[0][t] + vsp[1][t] + vsp[2][t] + vsp[3][t]) * (1e-6f/320.f);
  }
}

// ---------- decision: logits, argmax, one-hot (fp32 out), group ids ----------
__global__ void k_decide(const float* __restrict__ h2, const float* __restrict__ w3,
                         const float* __restrict__ b3, float* __restrict__ dec,
                         unsigned char* __restrict__ gid)
{
  int t = blockIdx.x*256 + threadIdx.x;   // 0..8191
  int b = t >> 8, s = t & 255;
  const float* hr = h2 + (size_t)t*192;
  float l0 = b3[0], l1 = b3[1];
  for (int c = 0; c < 192; ++c){
    float h = hr[c];
    l0 += h * w3[c];
    l1 += h * w3[192 + c];
  }
  int idx = (l1 > l0) ? 1 : 0;            // jnp.argmax: first max wins
  dec[t*2 + 0] = (idx == 0) ? 1.f : 0.f;
  dec[t*2 + 1] = (idx == 1) ? 1.f : 0.f;
  gid[b*320 + 64 + s] = (unsigned char)(2 + idx);
  if (s < 64) gid[b*320 + s] = 1;         // template tokens -> group 1
}

// ---------- bf16 MFMA GEMM, 128x128 tile, BK=64 (proj path, MODE=1) ----------
template<int MODE>
__global__ __launch_bounds__(256, 2)
void k_gemm(const u16* __restrict__ A, const u16* __restrict__ BT,
            const float* __restrict__ bias, float* __restrict__ outp,
            u16* __restrict__ Qg, u16* __restrict__ Kg, u16* __restrict__ Vg)
{
  __shared__ u16 As[128*64];   // [row][k] bf16, 128B rows, swizzled units
  __shared__ u16 Bs[128*64];
  int mB = blockIdx.x*128, nB = blockIdx.y*128;
  int t = threadIdx.x;
  int w = t >> 6, l = t & 63;
  int wr = w >> 1, wc = w & 1;
  int lm = l & 15, lq = l >> 4;

  f32x4 zero4 = {0.f,0.f,0.f,0.f};
  f32x4 acc[4][4];
  #pragma unroll
  for (int i = 0; i < 4; ++i)
    #pragma unroll
    for (int j = 0; j < 4; ++j) acc[i][j] = zero4;

  int srow = t >> 3;
  int su0  = t & 7;
  for (int k0 = 0; k0 < 768; k0 += 64){
    __syncthreads();
    #pragma unroll
    for (int s = 0; s < 4; ++s){
      int row = s*32 + srow;
      int su  = su0 ^ (row & 7);
      gld16(&A [(size_t)(mB+row)*768 + k0 + su*8], (char*)As + s*4096 + w*1024);
      gld16(&BT[(size_t)(nB+row)*768 + k0 + su*8], (char*)Bs + s*4096 + w*1024);
    }
    __syncthreads();
    short8 af[4][2], bfv[4][2];
    #pragma unroll
    for (int mt = 0; mt < 4; ++mt){
      int r = wr*64 + mt*16 + lm;
      #pragma unroll
      for (int hh = 0; hh < 2; ++hh)
        af[mt][hh] = *(const short8*)&As[r*64 + (((hh*4 + lq) ^ (r & 7)) << 3)];
    }
    #pragma unroll
    for (int nt = 0; nt < 4; ++nt){
      int r = wc*64 + nt*16 + lm;
      #pragma unroll
      for (int hh = 0; hh < 2; ++hh)
        bfv[nt][hh] = *(const short8*)&Bs[r*64 + (((hh*4 + lq) ^ (r & 7)) << 3)];
    }
    #pragma unroll
    for (int mt = 0; mt < 4; ++mt)
      #pragma unroll
      for (int nt = 0; nt < 4; ++nt){
        acc[mt][nt] = __builtin_amdgcn_mfma_f32_16x16x32_bf16(af[mt][0], bfv[nt][0], acc[mt][nt], 0, 0, 0);
        acc[mt][nt] = __builtin_amdgcn_mfma_f32_16x16x32_bf16(af[mt][1], bfv[nt][1], acc[mt][nt], 0, 0, 0);
      }
  }

  #pragma unroll
  for (int mt = 0; mt < 4; ++mt){
    #pragma unroll
    for (int nt = 0; nt < 4; ++nt){
      int coln  = nB + wc*64 + nt*16 + lm;
      int rbase = mB + wr*64 + mt*16 + lq*4;
      float bv = bias[coln];
      if (MODE == 0){
        int bidx = rbase / 320;
        int j = rbase - bidx*320;
        if (coln >= 1536){
          int h = (coln - 1536) >> 6, d = coln & 63;
          ushort4 pk;
          pk.x = f2bf(acc[mt][nt][0] + bv);
          pk.y = f2bf(acc[mt][nt][1] + bv);
          pk.z = f2bf(acc[mt][nt][2] + bv);
          pk.w = f2bf(acc[mt][nt][3] + bv);
          *(ushort4*)&Vg[((size_t)(bidx*12 + h)*64 + d)*320 + j] = pk;
        } else {
          bool isq = coln < 768;
          int ch = isq ? coln : (coln - 768);
          int h = ch >> 6, d = ch & 63;
          u16* dst = isq ? Qg : Kg;
          #pragma unroll
          for (int r = 0; r < 4; ++r)
            dst[((size_t)(bidx*12 + h)*320 + (j + r))*64 + d] = f2bf(acc[mt][nt][r] + bv);
        }
      } else {
        #pragma unroll
        for (int r = 0; r < 4; ++r)
          outp[(size_t)(rbase + r)*768 + coln] = acc[mt][nt][r] + bv;
      }
    }
  }
}

// ---------- attention: LDS-staged K/V (async, swizzled), in-register P ----------
// Grid 1920 = 8 XCD * 48 bh-groups * 5 qt (XCD-bijective; K/V L2-resident).
__global__ __launch_bounds__(256, 2)
void k_attn(const u16* __restrict__ Qg, const u16* __restrict__ Kg,
            const u16* __restrict__ Vg, const unsigned char* __restrict__ gid,
            const float* __restrict__ vsumg, u16* __restrict__ aout)
{
  __shared__ u16 lds[40960];            // 81920 B = K 40960 | V 40960
  u16* Ks = lds;                         // [320][64] swizzled
  u16* Vs = lds + 20480;                 // [64][320] swizzled

  int g = blockIdx.x;                    // 0..1919
  int xcd = g & 7, slot = g >> 3;        // 8 XCDs, 240 slots each
  int qt = slot % 5;
  int bh = (slot / 5) * 8 + xcd;         // bijective: (slot/5) in 0..47
  int b = bh / 12, h = bh % 12;
  int t = threadIdx.x, w = t >> 6, l = t & 63;
  int lm = l & 15, lq = l >> 4;
  const u16* Kbh = Kg + (size_t)bh*320*64;   // [j][d]
  const u16* Vbh = Vg + (size_t)bh*64*320;   // [d][j] (transposed)
  const u16* Qbh = Qg + (size_t)bh*320*64;   // [j][d]

  int qb = qt*64 + w*16;                 // wave's 16 q rows

  // --- early independent global loads (overlap with async staging) ---
  const u16* qp = Qbh + (size_t)(qb + lm)*64 + lq*8;
  short8 qf0 = *(const short8*)qp;       // B operand: Q[qb+lm][d]
  short8 qf1 = *(const short8*)(qp + 32);
  u32 gw[20];
  #pragma unroll
  for (int jt = 0; jt < 20; ++jt)
    gw[jt] = *(const u32*)&gid[b*320 + jt*16 + lq*4];
  int gi = gid[b*320 + qb + lm];         // this lane's q-row group id

  // --- stage K: rows 128B = 8 x 16B units; LDS[r][u] = K[r][u^(r&7)] ---
  #pragma unroll
  for (int c = 0; c < 10; ++c){
    int base = (w*10 + c) * 1024;              // wave-uniform LDS byte base
    int off  = base + l*16;                    // this lane's linear slot
    int r  = off >> 7;                         // K row (8 lanes per row)
    int u  = (off >> 4) & 7;                   // 16B unit within row
    const u16* src = Kbh + r*64 + ((u ^ (r & 7)) << 3);
    gld16(src, (char*)Ks + base);
  }
  // --- stage V: rows 640B = 40 x 16B units; LDS[d][u] = V[d][u^(d&7)] ---
  #pragma unroll
  for (int c = 0; c < 10; ++c){
    int base = (w*10 + c) * 1024;
    int off  = base + l*16;
    int d    = off / 640;                      // V row
    int uu   = (off - d*640) >> 4;             // 16B unit within row
    const u16* src = Vbh + d*320 + ((uu ^ (d & 7)) << 3);
    gld16(src, (char*)Vs + base);
  }
  __syncthreads();                             // drains vmcnt (staging done)

  const float cexp = 0.125f * 1.44269504088896340736f;  // scale * log2(e)
  f32x4 zero4 = {0.f,0.f,0.f,0.f};
  int swz = lm & 7;                            // row&7 for all this lane's rows

  // --- QK^T: 2 base addrs + offset immediates; zero per-iter addr VALU ---
  const u16* kb0 = Ks + lm*64 + (((lq    ) ^ swz) << 3);
  const u16* kb1 = Ks + lm*64 + (((lq + 4) ^ swz) << 3);
  f32x4 sacc[20];
  #pragma unroll
  for (int jt = 0; jt < 20; ++jt){
    short8 kf0 = *(const short8*)(kb0 + jt*1024);   // K[16jt+lm][8lq..]
    short8 kf1 = *(const short8*)(kb1 + jt*1024);   // K[16jt+lm][8lq+32..]
    f32x4 a = zero4;
    a = __builtin_amdgcn_mfma_f32_16x16x32_bf16(kf0, qf0, a, 0, 0, 0);
    a = __builtin_amdgcn_mfma_f32_16x16x32_bf16(kf1, qf1, a, 0, 0, 0);
    sacc[jt] = a;   // S[16jt+4lq+r][qb+lm]
  }
  // full-row max BEFORE masking (reference semantics); row = q = lm
  float m = -3.402823466e+38f;
  #pragma unroll
  for (int jt = 0; jt < 20; ++jt)
    m = fmaxf(m, fmaxf(fmaxf(sacc[jt][0], sacc[jt][1]),
                       fmaxf(sacc[jt][2], sacc[jt][3])));
  m = fmaxf(m, __shfl_xor(m, 16, 64));
  m = fmaxf(m, __shfl_xor(m, 32, 64));   // all lq copies of q=lm converge

  // --- exp+mask+pack fused with PV (one tile of P live at a time) ---
  bool gin3 = (gi != 3);
  float sm = 0.f;
  f32x4 oacc[4];
  #pragma unroll
  for (int nt = 0; nt < 4; ++nt) oacc[nt] = zero4;
  const u16* vb = Vs + lm*320 + ((lq & 1) << 2);   // + per-jt unit + nt*5120

  #pragma unroll
  for (int jt = 0; jt < 20; ++jt){
    u32 gwj = gw[jt];
    float e0, e1, e2, e3;
    {
      float ev = exp2f((sacc[jt][0] - m) * cexp);
      u32 gj = gwj & 255u;
      if (gin3 && (gj != 3u) && ((u32)gi != gj)) ev = 0.f;
      sm += ev; e0 = ev;
    }
    {
      float ev = exp2f((sacc[jt][1] - m) * cexp);
      u32 gj = (gwj >> 8) & 255u;
      if (gin3 && (gj != 3u) && ((u32)gi != gj)) ev = 0.f;
      sm += ev; e1 = ev;
    }
    {
      float ev = exp2f((sacc[jt][2] - m) * cexp);
      u32 gj = (gwj >> 16) & 255u;
      if (gin3 && (gj != 3u) && ((u32)gi != gj)) ev = 0.f;
      sm += ev; e2 = ev;
    }
    {
      float ev = exp2f((sacc[jt][3] - m) * cexp);
      u32 gj = gwj >> 24;
      if (gin3 && (gj != 3u) && ((u32)gi != gj)) ev = 0.f;
      sm += ev; e3 = ev;
    }
    u32 w0, w1;   // lo = src0 (RNE) — matches f2bf rounding
    asm("v_cvt_pk_bf16_f32 %0, %1, %2" : "=v"(w0) : "v"(e0), "v"(e1));
    asm("v_cvt_pk_bf16_f32 %0, %1, %2" : "=v"(w1) : "v"(e2), "v"(e3));
    union { u32 u[2]; s16x4 v; } pu;
    pu.u[0] = w0; pu.u[1] = w1;
    s16x4 pa = pu.v;                     // A[lm][k=16jt+4lq+e]
    int vu = (((2*jt + (lq >> 1)) ^ swz) << 3);   // swizzled 16B unit -> elems
    #pragma unroll
    for (int nt = 0; nt < 4; ++nt){
      s16x4 vf = *(const s16x4*)(vb + vu + nt*5120);  // V[16jt+4lq+e][nt*16+lm]
      oacc[nt] = mfma16x16x16bf16(pa, vf, oacc[nt]);
    }
  }
  sm += __shfl_xor(sm, 16, 64);
  sm += __shfl_xor(sm, 32, 64);
  float inv = 1.0f / (sm + 1e-6f);
  // redistribute: output C rows are 4lq+r; row-sum lives at lane lm=row
  float invO[4];
  #pragma unroll
  for (int r = 0; r < 4; ++r) invO[r] = __shfl(inv, lq*4 + r, 64);

  #pragma unroll
  for (int nt = 0; nt < 4; ++nt){
    int d = nt*16 + lm;
    float vs = vsumg[bh*64 + d];
    #pragma unroll
    for (int r = 0; r < 4; ++r){
      int row = qt*64 + w*16 + lq*4 + r;
      float v = (oacc[nt][r] + vs) * invO[r];
      aout[(size_t)(b*320 + row)*768 + h*64 + d] = f2bf(v);
    }
  }
}

// ---------- launch ----------
extern "C" void kernel_launch(void* const* d_in, const int* in_sizes, int n_in,
                              void* d_out, int out_size, void* d_ws, size_t ws_size,
                              hipStream_t stream)
{
  const float* x      = (const float*)d_in[0];
  const float* tmask  = (const float*)d_in[1];
  const float* qkv_w  = (const float*)d_in[2];
  const float* qkv_b  = (const float*)d_in[3];
  const float* proj_w = (const float*)d_in[4];
  const float* proj_b = (const float*)d_in[5];
  const float* dp1_w  = (const float*)d_in[6];
  const float* dp1_b  = (const float*)d_in[7];
  const float* dp2_w  = (const float*)d_in[8];
  const float* dp2_b  = (const float*)d_in[9];
  const float* dp3_w  = (const float*)d_in[10];
  const float* dp3_b  = (const float*)d_in[11];

  char* ws = (char*)d_ws;
  float* tgt    = (float*)(ws + 0);            // 32*768 f32        -> 98304
  float* tgtdp  = (float*)(ws + 98304);        // 32*384 f32        -> 147456
  float* h1     = (float*)(ws + 147456);       // 8192*384 f32      -> 12730368
  float* h2     = (float*)(ws + 12730368);     // 8192*192 f32      -> 19021824
  unsigned char* gid = (unsigned char*)(ws + 19021824);  // 10240   -> 19032064
  u16* xb     = (u16*)(ws + 19032064);         // 10240*768 bf16    -> 34760704
  u16* qkvwb  = (u16*)(ws + 34760704);         // 2304*768 bf16     -> 38299648
  u16* projwb = (u16*)(ws + 38299648);         // 768*768 bf16      -> 39479296
  u16* Qg     = (u16*)(ws + 39479296);         // [bh][320][64]     -> 55207936
  u16* Kg     = (u16*)(ws + 55207936);         //                   -> 70936576
  u16* Vg     = (u16*)(ws + 70936576);         // [bh][64][320]     -> 86665216
  u16* aout   = (u16*)(ws + 147456);           // bf16, overlaps dead h1/h2
  float* vsumg = (float*)(ws + 19032064);      // 384*64 f32 in DEAD xb region
                                               // (xb's only reader is k_fused1,
                                               //  which completes before
                                               //  k_fused2 writes vsumg; no
                                               //  overlap with live h2/gid)

  float* out = (float*)d_out;
  float* dec = out + 7864320;

  hipLaunchKernelGGL(k_cvt3, dim3(9984), dim3(256), 0, stream,
                     x, xb, qkv_w, qkvwb, proj_w, projwb);
  hipLaunchKernelGGL(k_tgt,   dim3(32, 12), dim3(64), 0, stream, x, tmask, tgt);
  hipLaunchKernelGGL(k_tgtdp, dim3(32), dim3(384), 0, stream, tgt, dp1_w, dp1_b, tgtdp);
  hipLaunchKernelGGL(k_fused1, dim3(2208), dim3(256), 0, stream,
                     x, dp1_w, tgtdp, h1, xb, qkvwb, qkv_b, Qg, Kg, Vg);
  hipLaunchKernelGGL(k_fused2, dim3(768), dim3(256), 0, stream,
                     h1, dp2_w, dp2_b, h2, Vg, vsumg);
  hipLaunchKernelGGL(k_decide, dim3(32), dim3(256), 0, stream, h2, dp3_w, dp3_b, dec, gid);
  hipLaunchKernelGGL(k_attn, dim3(1920), dim3(256), 0, stream, Qg, Kg, Vg, gid, vsumg, aout);
  hipLaunchKernelGGL((k_gemm<1>), dim3(80, 6), dim3(256), 0, stream,
                     aout, projwb, proj_b, out, (u16*)nullptr, (u16*)nullptr, (u16*)nullptr);
}

// Round 12
// 341.962 us; speedup vs baseline: 1.1003x; 1.1003x over previous
//
#include <hip/hip_runtime.h>
#include <hip/hip_bf16.h>

typedef unsigned short u16;
typedef unsigned int u32;
typedef unsigned long long u64;
typedef __attribute__((ext_vector_type(8))) short short8;
typedef __attribute__((ext_vector_type(4))) short s16x4;
typedef __attribute__((ext_vector_type(4))) float f32x4;

// ---------- helpers ----------
__device__ __forceinline__ float bf2f(u16 u){
  union { unsigned int i; float f; } v; v.i = ((unsigned int)u) << 16; return v.f;
}
__device__ __forceinline__ u16 f2bf(float f){
  union { float f; unsigned int i; } v; v.f = f;
  unsigned int x = v.i;
  return (u16)((x + 0x7fffu + ((x >> 16) & 1u)) >> 16);
}
__device__ __forceinline__ float gelu_exact(float x){
  return 0.5f * x * (1.0f + erff(x * 0.70710678118654752440f));
}
__device__ __forceinline__ void gld16(const void* g, void* l){
  __builtin_amdgcn_global_load_lds((const __attribute__((address_space(1))) void*)g,
                                   (__attribute__((address_space(3))) void*)l, 16, 0, 0);
}

// 16x16x16 bf16 MFMA (K=16): A-frag lane(lq,lm) holds A[lm][4*lq+e], e=0..3.
__device__ __forceinline__ f32x4 mfma16x16x16bf16(s16x4 a, s16x4 b, f32x4 c){
#if __has_builtin(__builtin_amdgcn_mfma_f32_16x16x16_bf16)
  return __builtin_amdgcn_mfma_f32_16x16x16_bf16(a, b, c, 0, 0, 0);
#elif __has_builtin(__builtin_amdgcn_mfma_f32_16x16x16bf16_1k)
  return __builtin_amdgcn_mfma_f32_16x16x16bf16_1k(a, b, c, 0, 0, 0);
#else
  asm volatile("v_mfma_f32_16x16x16_bf16 %0, %1, %2, %3\n\ts_nop 7\n\ts_nop 3"
               : "=v"(c) : "v"(a), "v"(b), "v"(c));
  return c;
#endif
}

// B=32 N=320 C=768 H=12 S=256 T=64 hd=64; ALL I/O fp32.

// ---------- merged: fp32->bf16 converts (x | qkv_w | proj_w) + tgt ----------
// Blocks 0..7679: x cvt. 7680..9407: qkv_w. 9408..9983: proj_w.
// 9984..10079: tgt_rep (32*768 threads; same per-(b,c) t-ascending sum as the
// old k_tgt -> bit-identical).
__global__ void k_cvt3t(const float* __restrict__ s0, u16* __restrict__ d0,
                        const float* __restrict__ s1, u16* __restrict__ d1,
                        const float* __restrict__ s2, u16* __restrict__ d2,
                        const float* __restrict__ x, const float* __restrict__ tmask,
                        float* __restrict__ tgt){
  int bx = blockIdx.x;
  if (bx < 9984){
    const float* src; u16* dst; int i;
    if (bx < 7680){ src = s0; dst = d0; i = bx*256 + threadIdx.x; }
    else if (bx < 9408){ src = s1; dst = d1; i = (bx - 7680)*256 + threadIdx.x; }
    else { src = s2; dst = d2; i = (bx - 9408)*256 + threadIdx.x; }
    float4 v = ((const float4*)src)[i];
    ushort4 p; p.x = f2bf(v.x); p.y = f2bf(v.y); p.z = f2bf(v.z); p.w = f2bf(v.w);
    ((ushort4*)dst)[i] = p;
  } else {
    int idx = (bx - 9984)*256 + threadIdx.x;   // 0..24575
    int b = idx / 768, c = idx - b*768;
    float s = 0.f;
    for (int t = 0; t < 64; ++t)
      s += x[(size_t)(b*320 + t)*768 + c] * tmask[b*64 + t];
    tgt[b*768 + c] = s * (1.0f/64.0f);
  }
}

// ---------- tgtdp[b][o] = dp1_b[o] + sum_c tgt[b][c]*dp1_w[o][768+c] ----------
__global__ void k_tgtdp(const float* __restrict__ tgt, const float* __restrict__ w1,
                        const float* __restrict__ b1, float* __restrict__ tgtdp){
  int b = blockIdx.x; int o = threadIdx.x;   // blockDim = 384
  float s = b1[o];
  const float* wr = w1 + (size_t)o*1536 + 768;
  const float* tr = tgt + b*768;
  for (int c = 0; c < 768; ++c) s += tr[c] * wr[c];
  tgtdp[b*384 + o] = s;
}

// ---------- FUSED: dp1 fp32 SGEMM (v0) + qkv bf16 MFMA GEMM (r6) ----------
// CONTIGUOUS block mapping (r9, verified 125us): blocks 0..767 dp1,
// 768..2207 qkv. r11's interleave doubled FETCH (L2 thrash from mixing
// panel-streaming block types per XCD) and cost +31us — reverted, frozen.
__global__ __launch_bounds__(256, 2)
void k_fused1(const float* __restrict__ A, const float* __restrict__ BT,
              const float* __restrict__ tgtdp, float* __restrict__ h1,
              const u16* __restrict__ GA, const u16* __restrict__ GB,
              const float* __restrict__ bias,
              u16* __restrict__ Qg, u16* __restrict__ Kg, u16* __restrict__ Vg)
{
  __shared__ char smem[32768];
  int bx = blockIdx.x;
  int t = threadIdx.x;
  if (bx < 768){
    // ================= dp1 sgemm path (v0) =================
    float (*As)[68] = (float(*)[68])smem;
    float (*Bs)[68] = (float(*)[68])(smem + 4352);
    int mB = (bx & 127)*64, nB = (bx >> 7)*64;
    int tx = t & 15, ty = t >> 4;
    float acc[4][4] = {};
    for (int k0 = 0; k0 < 768; k0 += 16){
      __syncthreads();
      {
        int m = t >> 2, kc = (t & 3) * 4;
        int ga = mB + m;
        ga = ((ga >> 8) * 320) + 64 + (ga & 255);       // REMAP
        float4 av = *(const float4*)&A[(size_t)ga*768 + k0 + kc];
        As[kc+0][m] = av.x; As[kc+1][m] = av.y; As[kc+2][m] = av.z; As[kc+3][m] = av.w;
        float4 bv = *(const float4*)&BT[(size_t)(nB+m)*1536 + k0 + kc];
        Bs[kc+0][m] = bv.x; Bs[kc+1][m] = bv.y; Bs[kc+2][m] = bv.z; Bs[kc+3][m] = bv.w;
      }
      __syncthreads();
      #pragma unroll
      for (int k = 0; k < 16; ++k){
        float4 av = *(const float4*)&As[k][ty*4];
        float4 bv = *(const float4*)&Bs[k][tx*4];
        float a4[4] = {av.x, av.y, av.z, av.w};
        float b4[4] = {bv.x, bv.y, bv.z, bv.w};
        #pragma unroll
        for (int i = 0; i < 4; ++i)
          #pragma unroll
          for (int j = 0; j < 4; ++j)
            acc[i][j] += a4[i] * b4[j];
      }
    }
    #pragma unroll
    for (int i = 0; i < 4; ++i){
      int row = mB + ty*4 + i;
      #pragma unroll
      for (int j = 0; j < 4; ++j){
        int n = nB + tx*4 + j;
        float base = tgtdp[(row >> 8)*384 + n];
        h1[(size_t)row*384 + n] = gelu_exact(acc[i][j] + base);
      }
    }
  } else {
    // ================= qkv bf16 MFMA path (r6) =================
    int i2 = bx - 768;
    u16* As = (u16*)smem;            // [128][64] swizzled
    u16* Bs = (u16*)(smem + 16384);
    int mB = (i2 % 80)*128, nB = (i2 / 80)*128;
    int w = t >> 6, l = t & 63;
    int wr = w >> 1, wc = w & 1;
    int lm = l & 15, lq = l >> 4;

    f32x4 zero4 = {0.f,0.f,0.f,0.f};
    f32x4 acc[4][4];
    #pragma unroll
    for (int i = 0; i < 4; ++i)
      #pragma unroll
      for (int j = 0; j < 4; ++j) acc[i][j] = zero4;

    int srow = t >> 3;            // 0..31 within shot
    int su0  = t & 7;             // phys unit this lane fills
    for (int k0 = 0; k0 < 768; k0 += 64){
      __syncthreads();
      #pragma unroll
      for (int s = 0; s < 4; ++s){
        int row = s*32 + srow;
        int su  = su0 ^ (row & 7);
        gld16(&GA[(size_t)(mB+row)*768 + k0 + su*8], (char*)As + s*4096 + w*1024);
        gld16(&GB[(size_t)(nB+row)*768 + k0 + su*8], (char*)Bs + s*4096 + w*1024);
      }
      __syncthreads();
      short8 af[4][2], bfv[4][2];
      #pragma unroll
      for (int mt = 0; mt < 4; ++mt){
        int r = wr*64 + mt*16 + lm;
        #pragma unroll
        for (int hh = 0; hh < 2; ++hh)
          af[mt][hh] = *(const short8*)&As[r*64 + (((hh*4 + lq) ^ (r & 7)) << 3)];
      }
      #pragma unroll
      for (int nt = 0; nt < 4; ++nt){
        int r = wc*64 + nt*16 + lm;
        #pragma unroll
        for (int hh = 0; hh < 2; ++hh)
          bfv[nt][hh] = *(const short8*)&Bs[r*64 + (((hh*4 + lq) ^ (r & 7)) << 3)];
      }
      #pragma unroll
      for (int mt = 0; mt < 4; ++mt)
        #pragma unroll
        for (int nt = 0; nt < 4; ++nt){
          acc[mt][nt] = __builtin_amdgcn_mfma_f32_16x16x32_bf16(af[mt][0], bfv[nt][0], acc[mt][nt], 0, 0, 0);
          acc[mt][nt] = __builtin_amdgcn_mfma_f32_16x16x32_bf16(af[mt][1], bfv[nt][1], acc[mt][nt], 0, 0, 0);
        }
    }
    // epilogue: C layout col=lane&15, row=(lane>>4)*4+reg
    #pragma unroll
    for (int mt = 0; mt < 4; ++mt){
      #pragma unroll
      for (int nt = 0; nt < 4; ++nt){
        int coln  = nB + wc*64 + nt*16 + lm;
        int rbase = mB + wr*64 + mt*16 + lq*4;
        float bv = bias[coln];
        int bidx = rbase / 320;
        int j = rbase - bidx*320;
        if (coln >= 1536){
          int h = (coln - 1536) >> 6, d = coln & 63;
          ushort4 pk;
          pk.x = f2bf(acc[mt][nt][0] + bv);
          pk.y = f2bf(acc[mt][nt][1] + bv);
          pk.z = f2bf(acc[mt][nt][2] + bv);
          pk.w = f2bf(acc[mt][nt][3] + bv);
          *(ushort4*)&Vg[((size_t)(bidx*12 + h)*64 + d)*320 + j] = pk;
        } else {
          bool isq = coln < 768;
          int ch = isq ? coln : (coln - 768);
          int h = ch >> 6, d = ch & 63;
          u16* dst = isq ? Qg : Kg;
          #pragma unroll
          for (int r = 0; r < 4; ++r)
            dst[((size_t)(bidx*12 + h)*320 + (j + r))*64 + d] = f2bf(acc[mt][nt][r] + bv);
        }
      }
    }
  }
}

// ---------- FUSED: dp2 fp32 SGEMM (v0) + vsum ----------
// Blocks 0..383: dp2 (M=8192 N=192 K=384, HASB). Blocks 384..767: vsum.
// vsumg lives in the DEAD xb region (ws+19032064) — no overlap with h2.
__global__ __launch_bounds__(256)
void k_fused2(const float* __restrict__ A, const float* __restrict__ BT,
              const float* __restrict__ bias, float* __restrict__ out,
              const u16* __restrict__ Vg, float* __restrict__ vsumg)
{
  __shared__ char smem[8704];
  int bx = blockIdx.x;
  int t = threadIdx.x;
  if (bx < 384){
    // ---- dp2 sgemm v0: mB=(bx&127)*64, nB=(bx>>7)*64 ----
    float (*As)[68] = (float(*)[68])smem;
    float (*Bs)[68] = (float(*)[68])(smem + 4352);
    int mB = (bx & 127)*64, nB = (bx >> 7)*64;
    int tx = t & 15, ty = t >> 4;
    float acc[4][4] = {};
    for (int k0 = 0; k0 < 384; k0 += 16){
      __syncthreads();
      {
        int m = t >> 2, kc = (t & 3) * 4;
        float4 av = *(const float4*)&A[(size_t)(mB+m)*384 + k0 + kc];
        As[kc+0][m] = av.x; As[kc+1][m] = av.y; As[kc+2][m] = av.z; As[kc+3][m] = av.w;
        float4 bv = *(const float4*)&BT[(size_t)(nB+m)*384 + k0 + kc];
        Bs[kc+0][m] = bv.x; Bs[kc+1][m] = bv.y; Bs[kc+2][m] = bv.z; Bs[kc+3][m] = bv.w;
      }
      __syncthreads();
      #pragma unroll
      for (int k = 0; k < 16; ++k){
        float4 av = *(const float4*)&As[k][ty*4];
        float4 bv = *(const float4*)&Bs[k][tx*4];
        float a4[4] = {av.x, av.y, av.z, av.w};
        float b4[4] = {bv.x, bv.y, bv.z, bv.w};
        #pragma unroll
        for (int i = 0; i < 4; ++i)
          #pragma unroll
          for (int j = 0; j < 4; ++j)
            acc[i][j] += a4[i] * b4[j];
      }
    }
    #pragma unroll
    for (int i = 0; i < 4; ++i){
      int row = mB + ty*4 + i;
      #pragma unroll
      for (int j = 0; j < 4; ++j){
        int n = nB + tx*4 + j;
        out[(size_t)row*192 + n] = gelu_exact(acc[i][j] + bias[n]);
      }
    }
  } else {
    // ---- vsum: bh = bx - 384 ----
    float (*vsp)[64] = (float(*)[64])smem;
    int bh = bx - 384;
    int w = t >> 6, l = t & 63;
    const u16* vr = Vg + (size_t)bh*64*320 + (size_t)l*320 + w*80;
    float s = 0.f;
    for (int j8 = 0; j8 < 10; ++j8){
      short8 v = *(const short8*)&vr[j8*8];
      #pragma unroll
      for (int e = 0; e < 8; ++e) s += bf2f((u16)v[e]);
    }
    vsp[w][l] = s;
    __syncthreads();
    if (t < 64) vsumg[bh*64 + t] = (vsp[0][t] + vsp[1][t] + vsp[2][t] + vsp[3][t]) * (1e-6f/320.f);
  }
}

// ---------- decision: logits, argmax, one-hot (fp32 out), group ids ----------
__global__ void k_decide(const float* __restrict__ h2, const float* __restrict__ w3,
                         const float* __restrict__ b3, float* __restrict__ dec,
                         unsigned char* __restrict__ gid)
{
  int t = blockIdx.x*256 + threadIdx.x;   // 0..8191
  int b = t >> 8, s = t & 255;
  const float* hr = h2 + (size_t)t*192;
  float l0 = b3[0], l1 = b3[1];
  for (int c = 0; c < 192; ++c){
    float h = hr[c];
    l0 += h * w3[c];
    l1 += h * w3[192 + c];
  }
  int idx = (l1 > l0) ? 1 : 0;            // jnp.argmax: first max wins
  dec[t*2 + 0] = (idx == 0) ? 1.f : 0.f;
  dec[t*2 + 1] = (idx == 1) ? 1.f : 0.f;
  gid[b*320 + 64 + s] = (unsigned char)(2 + idx);
  if (s < 64) gid[b*320 + s] = 1;         // template tokens -> group 1
}

// ---------- bf16 MFMA GEMM, 128x128 tile, BK=64 (proj path, MODE=1) ----------
template<int MODE>
__global__ __launch_bounds__(256, 2)
void k_gemm(const u16* __restrict__ A, const u16* __restrict__ BT,
            const float* __restrict__ bias, float* __restrict__ outp,
            u16* __restrict__ Qg, u16* __restrict__ Kg, u16* __restrict__ Vg)
{
  __shared__ u16 As[128*64];   // [row][k] bf16, 128B rows, swizzled units
  __shared__ u16 Bs[128*64];
  int mB = blockIdx.x*128, nB = blockIdx.y*128;
  int t = threadIdx.x;
  int w = t >> 6, l = t & 63;
  int wr = w >> 1, wc = w & 1;
  int lm = l & 15, lq = l >> 4;

  f32x4 zero4 = {0.f,0.f,0.f,0.f};
  f32x4 acc[4][4];
  #pragma unroll
  for (int i = 0; i < 4; ++i)
    #pragma unroll
    for (int j = 0; j < 4; ++j) acc[i][j] = zero4;

  int srow = t >> 3;
  int su0  = t & 7;
  for (int k0 = 0; k0 < 768; k0 += 64){
    __syncthreads();
    #pragma unroll
    for (int s = 0; s < 4; ++s){
      int row = s*32 + srow;
      int su  = su0 ^ (row & 7);
      gld16(&A [(size_t)(mB+row)*768 + k0 + su*8], (char*)As + s*4096 + w*1024);
      gld16(&BT[(size_t)(nB+row)*768 + k0 + su*8], (char*)Bs + s*4096 + w*1024);
    }
    __syncthreads();
    short8 af[4][2], bfv[4][2];
    #pragma unroll
    for (int mt = 0; mt < 4; ++mt){
      int r = wr*64 + mt*16 + lm;
      #pragma unroll
      for (int hh = 0; hh < 2; ++hh)
        af[mt][hh] = *(const short8*)&As[r*64 + (((hh*4 + lq) ^ (r & 7)) << 3)];
    }
    #pragma unroll
    for (int nt = 0; nt < 4; ++nt){
      int r = wc*64 + nt*16 + lm;
      #pragma unroll
      for (int hh = 0; hh < 2; ++hh)
        bfv[nt][hh] = *(const short8*)&Bs[r*64 + (((hh*4 + lq) ^ (r & 7)) << 3)];
    }
    #pragma unroll
    for (int mt = 0; mt < 4; ++mt)
      #pragma unroll
      for (int nt = 0; nt < 4; ++nt){
        acc[mt][nt] = __builtin_amdgcn_mfma_f32_16x16x32_bf16(af[mt][0], bfv[nt][0], acc[mt][nt], 0, 0, 0);
        acc[mt][nt] = __builtin_amdgcn_mfma_f32_16x16x32_bf16(af[mt][1], bfv[nt][1], acc[mt][nt], 0, 0, 0);
      }
  }

  #pragma unroll
  for (int mt = 0; mt < 4; ++mt){
    #pragma unroll
    for (int nt = 0; nt < 4; ++nt){
      int coln  = nB + wc*64 + nt*16 + lm;
      int rbase = mB + wr*64 + mt*16 + lq*4;
      float bv = bias[coln];
      if (MODE == 0){
        int bidx = rbase / 320;
        int j = rbase - bidx*320;
        if (coln >= 1536){
          int h = (coln - 1536) >> 6, d = coln & 63;
          ushort4 pk;
          pk.x = f2bf(acc[mt][nt][0] + bv);
          pk.y = f2bf(acc[mt][nt][1] + bv);
          pk.z = f2bf(acc[mt][nt][2] + bv);
          pk.w = f2bf(acc[mt][nt][3] + bv);
          *(ushort4*)&Vg[((size_t)(bidx*12 + h)*64 + d)*320 + j] = pk;
        } else {
          bool isq = coln < 768;
          int ch = isq ? coln : (coln - 768);
          int h = ch >> 6, d = ch & 63;
          u16* dst = isq ? Qg : Kg;
          #pragma unroll
          for (int r = 0; r < 4; ++r)
            dst[((size_t)(bidx*12 + h)*320 + (j + r))*64 + d] = f2bf(acc[mt][nt][r] + bv);
        }
      } else {
        #pragma unroll
        for (int r = 0; r < 4; ++r)
          outp[(size_t)(rbase + r)*768 + coln] = acc[mt][nt][r] + bv;
      }
    }
  }
}

// ---------- attention: LDS-staged K/V (async, swizzled), in-register P ----------
// Grid 1920 = 8 XCD * 48 bh-groups * 5 qt (XCD-bijective; K/V L2-resident).
__global__ __launch_bounds__(256, 2)
void k_attn(const u16* __restrict__ Qg, const u16* __restrict__ Kg,
            const u16* __restrict__ Vg, const unsigned char* __restrict__ gid,
            const float* __restrict__ vsumg, u16* __restrict__ aout)
{
  __shared__ u16 lds[40960];            // 81920 B = K 40960 | V 40960
  u16* Ks = lds;                         // [320][64] swizzled
  u16* Vs = lds + 20480;                 // [64][320] swizzled

  int g = blockIdx.x;                    // 0..1919
  int xcd = g & 7, slot = g >> 3;        // 8 XCDs, 240 slots each
  int qt = slot % 5;
  int bh = (slot / 5) * 8 + xcd;         // bijective: (slot/5) in 0..47
  int b = bh / 12, h = bh % 12;
  int t = threadIdx.x, w = t >> 6, l = t & 63;
  int lm = l & 15, lq = l >> 4;
  const u16* Kbh = Kg + (size_t)bh*320*64;   // [j][d]
  const u16* Vbh = Vg + (size_t)bh*64*320;   // [d][j] (transposed)
  const u16* Qbh = Qg + (size_t)bh*320*64;   // [j][d]

  int qb = qt*64 + w*16;                 // wave's 16 q rows

  // --- early independent global loads (overlap with async staging) ---
  const u16* qp = Qbh + (size_t)(qb + lm)*64 + lq*8;
  short8 qf0 = *(const short8*)qp;       // B operand: Q[qb+lm][d]
  short8 qf1 = *(const short8*)(qp + 32);
  u32 gw[20];
  #pragma unroll
  for (int jt = 0; jt < 20; ++jt)
    gw[jt] = *(const u32*)&gid[b*320 + jt*16 + lq*4];
  int gi = gid[b*320 + qb + lm];         // this lane's q-row group id

  // --- stage K: rows 128B = 8 x 16B units; LDS[r][u] = K[r][u^(r&7)] ---
  #pragma unroll
  for (int c = 0; c < 10; ++c){
    int base = (w*10 + c) * 1024;              // wave-uniform LDS byte base
    int off  = base + l*16;                    // this lane's linear slot
    int r  = off >> 7;                         // K row (8 lanes per row)
    int u  = (off >> 4) & 7;                   // 16B unit within row
    const u16* src = Kbh + r*64 + ((u ^ (r & 7)) << 3);
    gld16(src, (char*)Ks + base);
  }
  // --- stage V: rows 640B = 40 x 16B units; LDS[d][u] = V[d][u^(d&7)] ---
  #pragma unroll
  for (int c = 0; c < 10; ++c){
    int base = (w*10 + c) * 1024;
    int off  = base + l*16;
    int d    = off / 640;                      // V row
    int uu   = (off - d*640) >> 4;             // 16B unit within row
    const u16* src = Vbh + d*320 + ((uu ^ (d & 7)) << 3);
    gld16(src, (char*)Vs + base);
  }
  __syncthreads();                             // drains vmcnt (staging done)

  const float cexp = 0.125f * 1.44269504088896340736f;  // scale * log2(e)
  f32x4 zero4 = {0.f,0.f,0.f,0.f};
  int swz = lm & 7;                            // row&7 for all this lane's rows

  // --- QK^T: 2 base addrs + offset immediates; zero per-iter addr VALU ---
  const u16* kb0 = Ks + lm*64 + (((lq    ) ^ swz) << 3);
  const u16* kb1 = Ks + lm*64 + (((lq + 4) ^ swz) << 3);
  f32x4 sacc[20];
  #pragma unroll
  for (int jt = 0; jt < 20; ++jt){
    short8 kf0 = *(const short8*)(kb0 + jt*1024);   // K[16jt+lm][8lq..]
    short8 kf1 = *(const short8*)(kb1 + jt*1024);   // K[16jt+lm][8lq+32..]
    f32x4 a = zero4;
    a = __builtin_amdgcn_mfma_f32_16x16x32_bf16(kf0, qf0, a, 0, 0, 0);
    a = __builtin_amdgcn_mfma_f32_16x16x32_bf16(kf1, qf1, a, 0, 0, 0);
    sacc[jt] = a;   // S[16jt+4lq+r][qb+lm]
  }
  // full-row max BEFORE masking (reference semantics); row = q = lm
  float m = -3.402823466e+38f;
  #pragma unroll
  for (int jt = 0; jt < 20; ++jt)
    m = fmaxf(m, fmaxf(fmaxf(sacc[jt][0], sacc[jt][1]),
                       fmaxf(sacc[jt][2], sacc[jt][3])));
  m = fmaxf(m, __shfl_xor(m, 16, 64));
  m = fmaxf(m, __shfl_xor(m, 32, 64));   // all lq copies of q=lm converge

  // --- exp+mask+pack fused with PV (one tile of P live at a time) ---
  bool gin3 = (gi != 3);
  float sm = 0.f;
  f32x4 oacc[4];
  #pragma unroll
  for (int nt = 0; nt < 4; ++nt) oacc[nt] = zero4;
  const u16* vb = Vs + lm*320 + ((lq & 1) << 2);   // + per-jt unit + nt*5120

  #pragma unroll
  for (int jt = 0; jt < 20; ++jt){
    u32 gwj = gw[jt];
    float e0, e1, e2, e3;
    {
      float ev = exp2f((sacc[jt][0] - m) * cexp);
      u32 gj = gwj & 255u;
      if (gin3 && (gj != 3u) && ((u32)gi != gj)) ev = 0.f;
      sm += ev; e0 = ev;
    }
    {
      float ev = exp2f((sacc[jt][1] - m) * cexp);
      u32 gj = (gwj >> 8) & 255u;
      if (gin3 && (gj != 3u) && ((u32)gi != gj)) ev = 0.f;
      sm += ev; e1 = ev;
    }
    {
      float ev = exp2f((sacc[jt][2] - m) * cexp);
      u32 gj = (gwj >> 16) & 255u;
      if (gin3 && (gj != 3u) && ((u32)gi != gj)) ev = 0.f;
      sm += ev; e2 = ev;
    }
    {
      float ev = exp2f((sacc[jt][3] - m) * cexp);
      u32 gj = gwj >> 24;
      if (gin3 && (gj != 3u) && ((u32)gi != gj)) ev = 0.f;
      sm += ev; e3 = ev;
    }
    u32 w0, w1;   // lo = src0 (RNE) — matches f2bf rounding
    asm("v_cvt_pk_bf16_f32 %0, %1, %2" : "=v"(w0) : "v"(e0), "v"(e1));
    asm("v_cvt_pk_bf16_f32 %0, %1, %2" : "=v"(w1) : "v"(e2), "v"(e3));
    union { u32 u[2]; s16x4 v; } pu;
    pu.u[0] = w0; pu.u[1] = w1;
    s16x4 pa = pu.v;                     // A[lm][k=16jt+4lq+e]
    int vu = (((2*jt + (lq >> 1)) ^ swz) << 3);   // swizzled 16B unit -> elems
    #pragma unroll
    for (int nt = 0; nt < 4; ++nt){
      s16x4 vf = *(const s16x4*)(vb + vu + nt*5120);  // V[16jt+4lq+e][nt*16+lm]
      oacc[nt] = mfma16x16x16bf16(pa, vf, oacc[nt]);
    }
  }
  sm += __shfl_xor(sm, 16, 64);
  sm += __shfl_xor(sm, 32, 64);
  float inv = 1.0f / (sm + 1e-6f);
  // redistribute: output C rows are 4lq+r; row-sum lives at lane lm=row
  float invO[4];
  #pragma unroll
  for (int r = 0; r < 4; ++r) invO[r] = __shfl(inv, lq*4 + r, 64);

  #pragma unroll
  for (int nt = 0; nt < 4; ++nt){
    int d = nt*16 + lm;
    float vs = vsumg[bh*64 + d];
    #pragma unroll
    for (int r = 0; r < 4; ++r){
      int row = qt*64 + w*16 + lq*4 + r;
      float v = (oacc[nt][r] + vs) * invO[r];
      aout[(size_t)(b*320 + row)*768 + h*64 + d] = f2bf(v);
    }
  }
}

// ---------- launch ----------
extern "C" void kernel_launch(void* const* d_in, const int* in_sizes, int n_in,
                              void* d_out, int out_size, void* d_ws, size_t ws_size,
                              hipStream_t stream)
{
  const float* x      = (const float*)d_in[0];
  const float* tmask  = (const float*)d_in[1];
  const float* qkv_w  = (const float*)d_in[2];
  const float* qkv_b  = (const float*)d_in[3];
  const float* proj_w = (const float*)d_in[4];
  const float* proj_b = (const float*)d_in[5];
  const float* dp1_w  = (const float*)d_in[6];
  const float* dp1_b  = (const float*)d_in[7];
  const float* dp2_w  = (const float*)d_in[8];
  const float* dp2_b  = (const float*)d_in[9];
  const float* dp3_w  = (const float*)d_in[10];
  const float* dp3_b  = (const float*)d_in[11];

  char* ws = (char*)d_ws;
  float* tgt    = (float*)(ws + 0);            // 32*768 f32        -> 98304
  float* tgtdp  = (float*)(ws + 98304);        // 32*384 f32        -> 147456
  float* h1     = (float*)(ws + 147456);       // 8192*384 f32      -> 12730368
  float* h2     = (float*)(ws + 12730368);     // 8192*192 f32      -> 19021824
  unsigned char* gid = (unsigned char*)(ws + 19021824);  // 10240   -> 19032064
  u16* xb     = (u16*)(ws + 19032064);         // 10240*768 bf16    -> 34760704
  u16* qkvwb  = (u16*)(ws + 34760704);         // 2304*768 bf16     -> 38299648
  u16* projwb = (u16*)(ws + 38299648);         // 768*768 bf16      -> 39479296
  u16* Qg     = (u16*)(ws + 39479296);         // [bh][320][64]     -> 55207936
  u16* Kg     = (u16*)(ws + 55207936);         //                   -> 70936576
  u16* Vg     = (u16*)(ws + 70936576);         // [bh][64][320]     -> 86665216
  u16* aout   = (u16*)(ws + 147456);           // bf16, overlaps dead h1/h2
  float* vsumg = (float*)(ws + 19032064);      // 384*64 f32 in DEAD xb region
                                               // (xb's only reader k_fused1
                                               //  completes before k_fused2
                                               //  writes vsumg; no overlap
                                               //  with live h2/gid)

  float* out = (float*)d_out;
  float* dec = out + 7864320;

  hipLaunchKernelGGL(k_cvt3t, dim3(10080), dim3(256), 0, stream,
                     x, xb, qkv_w, qkvwb, proj_w, projwb, x, tmask, tgt);
  hipLaunchKernelGGL(k_tgtdp, dim3(32), dim3(384), 0, stream, tgt, dp1_w, dp1_b, tgtdp);
  hipLaunchKernelGGL(k_fused1, dim3(2208), dim3(256), 0, stream,
                     x, dp1_w, tgtdp, h1, xb, qkvwb, qkv_b, Qg, Kg, Vg);
  hipLaunchKernelGGL(k_fused2, dim3(768), dim3(256), 0, stream,
                     h1, dp2_w, dp2_b, h2, Vg, vsumg);
  hipLaunchKernelGGL(k_decide, dim3(32), dim3(256), 0, stream, h2, dp3_w, dp3_b, dec, gid);
  hipLaunchKernelGGL(k_attn, dim3(1920), dim3(256), 0, stream, Qg, Kg, Vg, gid, vsumg, aout);
  hipLaunchKernelGGL((k_gemm<1>), dim3(80, 6), dim3(256), 0, stream,
                     aout, projwb, proj_b, out, (u16*)nullptr, (u16*)nullptr, (u16*)nullptr);
}